// Round 3
// baseline (4041.577 us; speedup 1.0000x reference)
//
#include <hip/hip_runtime.h>
#include <math.h>

// CharacterBertCharacterCNN — Round 3
// conv fp32 (balanced virtual channels, sliding-window acc) -> t0h (f16)
// highway x2 + proj as f16 MFMA GEMMs (m97 structure: 128x128 tile, BK=64,
// global_load_lds w16, 2-barrier loop), weights transposed to [N][K] f16
// into a single reused buffer (stream-serialized).
//
// ws layout (bytes):
//   t0h  @ 0         : 4096*2048 f16 = 16,777,216
//   t1h  @ 16777216  : 16,777,216
//   wbuf @ 33554432  : 16,777,216   (holds w0t, then w1t, then pwt)
//   total 50,331,648 (< 67 MB proven available in Round 1)

#define NTOK 4096
#define NCHAR 50
#define EMB 16
#define TF 2048
#define HID 768
#define TPB 16      // tokens per conv block
#define BK 64       // GEMM k-tile

typedef float f32x4 __attribute__((ext_vector_type(4)));
typedef _Float16 f16x8 __attribute__((ext_vector_type(8)));
typedef _Float16 half_t;

__device__ __forceinline__ void gl_lds16(const void* g, void* l) {
  __builtin_amdgcn_global_load_lds(
      (const __attribute__((address_space(1))) void*)g,
      (__attribute__((address_space(3))) void*)l, 16, 0, 0);
}

// ------------------------------------------------- transpose + f32->f16 ----
// src [R][C] f32  ->  dst [C][R] f16 ; grid (C/64, R/64), 256 threads.
__global__ __launch_bounds__(256) void tcvt_kernel(
    const float* __restrict__ src, half_t* __restrict__ dst, int R, int C) {
  __shared__ half_t tile[64][72];   // 72-half stride: 144B = 9*16B, keeps 16B align
  const int tid = threadIdx.x;
  const int r0 = blockIdx.y * 64, c0 = blockIdx.x * 64;
  const int rr = tid >> 4, cq = tid & 15;
#pragma unroll
  for (int p = 0; p < 4; ++p) {
    const int r = rr + p * 16;
    const float4 v = *(const float4*)&src[(size_t)(r0 + r) * C + c0 + cq * 4];
    tile[cq * 4 + 0][r] = (half_t)v.x;
    tile[cq * 4 + 1][r] = (half_t)v.y;
    tile[cq * 4 + 2][r] = (half_t)v.z;
    tile[cq * 4 + 3][r] = (half_t)v.w;
  }
  __syncthreads();
#pragma unroll
  for (int p = 0; p < 2; ++p) {
    const int item = p * 256 + tid;
    const int c = item >> 3, ch = item & 7;
    const f16x8 v = *(const f16x8*)&tile[c][ch * 8];
    *(f16x8*)&dst[(size_t)(c0 + c) * R + r0 + ch * 8] = v;
  }
}

// ---------------------------------------------------------------- conv ----
// Sliding-window accumulator: position p is live only for rows p..p+W-1, so
// W registers suffice (slot p%W). All indices compile-time after unroll.

template<int W, int P0, int P1>
__device__ __forceinline__ float conv_win(const float* wreg,
                                          const float (*emb)[EMB]) {
  float acc[W];
  float m = -1e30f;
#pragma unroll
  for (int r = P0; r < P1 + W - 1; ++r) {   // rows feeding positions [P0,P1)
    float row[EMB];
#pragma unroll
    for (int q = 0; q < 4; ++q) {
      const float4 v = *(const float4*)&emb[r][q * 4];
      row[q * 4 + 0] = v.x; row[q * 4 + 1] = v.y;
      row[q * 4 + 2] = v.z; row[q * 4 + 3] = v.w;
    }
#pragma unroll
    for (int j = 0; j < W; ++j) {
      const int p = r - j;                   // compile-time after unroll
      if (p >= P0 && p < P1) {
        const int s = p % W;
        if (j == 0) acc[s] = 0.f;            // position p starts at row r==p
#pragma unroll
        for (int i = 0; i < EMB; ++i)
          acc[s] = fmaf(row[i], wreg[i * W + j], acc[s]);
        if (j == W - 1) m = fmaxf(m, acc[s]); // position p done at row p+W-1
      }
    }
  }
  return m;
}

template<int W>
__device__ __forceinline__ void load_wreg(const float* __restrict__ wp, float* wreg) {
#pragma unroll
  for (int x = 0; x < 4 * W; ++x) {
    const float4 v = *(const float4*)(wp + 4 * x);
    wreg[4 * x + 0] = v.x; wreg[4 * x + 1] = v.y;
    wreg[4 * x + 2] = v.z; wreg[4 * x + 3] = v.w;
  }
}

// virtual channels: W1(32) W2(32) W3(64) W4(128) whole; W5/W6/W7 split into
// two position-halves. In every W>=5 block: tid<128 -> ph0, tid>=128 -> ph1
// (wave-uniform); partial max combined via LDS.
__global__ __launch_bounds__(256, 3) void conv_kernel(
    const int* __restrict__ ids, const float* __restrict__ cemb,
    const float* __restrict__ w0, const float* __restrict__ b0,
    const float* __restrict__ w1, const float* __restrict__ b1,
    const float* __restrict__ w2, const float* __restrict__ b2,
    const float* __restrict__ w3, const float* __restrict__ b3,
    const float* __restrict__ w4, const float* __restrict__ b4,
    const float* __restrict__ w5, const float* __restrict__ b5,
    const float* __restrict__ w6, const float* __restrict__ b6,
    half_t* __restrict__ tout) {
  __shared__ float emb_s[NCHAR][EMB];
  __shared__ float pmax[128];
  const int tid = threadIdx.x;
  const int vc = blockIdx.y * 256 + tid;   // 0..3839

  int W, lc, ph, c;
  const float *wb, *bb;
  if      (vc < 32)   { W = 1; lc = vc;        ph = 0; wb = w0; bb = b0; c = lc; }
  else if (vc < 64)   { W = 2; lc = vc - 32;   ph = 0; wb = w1; bb = b1; c = 32 + lc; }
  else if (vc < 128)  { W = 3; lc = vc - 64;   ph = 0; wb = w2; bb = b2; c = 64 + lc; }
  else if (vc < 256)  { W = 4; lc = vc - 128;  ph = 0; wb = w3; bb = b3; c = 128 + lc; }
  else if (vc < 768)  { const int u = vc - 256;
                        W = 5; lc = (u >> 8) * 128 + (u & 127); ph = (u >> 7) & 1;
                        wb = w4; bb = b4; c = 256 + lc; }
  else if (vc < 1792) { const int u = vc - 768;
                        W = 6; lc = (u >> 8) * 128 + (u & 127); ph = (u >> 7) & 1;
                        wb = w5; bb = b5; c = 512 + lc; }
  else                { const int u = vc - 1792;
                        W = 7; lc = (u >> 8) * 128 + (u & 127); ph = (u >> 7) & 1;
                        wb = w6; bb = b6; c = 1024 + lc; }

  const float* wp = wb + (size_t)lc * EMB * W;
  const float bias = bb[lc];
  const int lcl = tid & 127;
  float wreg[112];
  switch (W) {
    case 1: load_wreg<1>(wp, wreg); break;
    case 2: load_wreg<2>(wp, wreg); break;
    case 3: load_wreg<3>(wp, wreg); break;
    case 4: load_wreg<4>(wp, wreg); break;
    case 5: load_wreg<5>(wp, wreg); break;
    case 6: load_wreg<6>(wp, wreg); break;
    default: load_wreg<7>(wp, wreg); break;
  }

  const int tok0 = blockIdx.x * TPB;
  for (int tt = 0; tt < TPB; ++tt) {
    const int tok = tok0 + tt;
    __syncthreads();                      // protect emb_s / pmax reuse
    if (tid < 200) {                      // 50 rows x 4 quads
      const int row = tid >> 2, q = tid & 3;
      const int id = ids[tok * NCHAR + row];
      *(float4*)&emb_s[row][q * 4] = *(const float4*)&cemb[id * EMB + q * 4];
    }
    __syncthreads();
    float res;
    switch (W) {
      case 1: res = conv_win<1, 0, 50>(wreg, emb_s); break;
      case 2: res = conv_win<2, 0, 49>(wreg, emb_s); break;
      case 3: res = conv_win<3, 0, 48>(wreg, emb_s); break;
      case 4: res = conv_win<4, 0, 47>(wreg, emb_s); break;
      case 5: res = ph ? conv_win<5, 23, 46>(wreg, emb_s)
                       : conv_win<5, 0, 23>(wreg, emb_s); break;
      case 6: res = ph ? conv_win<6, 23, 45>(wreg, emb_s)
                       : conv_win<6, 0, 23>(wreg, emb_s); break;
      default: res = ph ? conv_win<7, 22, 44>(wreg, emb_s)
                        : conv_win<7, 0, 22>(wreg, emb_s); break;
    }
    if (W >= 5) {                         // block-uniform condition
      if (ph) pmax[lcl] = res;
      __syncthreads();
      if (ph == 0) {
        res = fmaxf(res, pmax[lcl]);
        tout[(size_t)tok * TF + c] = (half_t)fmaxf(res + bias, 0.f);
      }
    } else {
      tout[(size_t)tok * TF + c] = (half_t)fmaxf(res + bias, 0.f);
    }
  }
}

// ------------------------------------------------------------- highway ----
// A = tin [4096][2048] f16 row-major; B^T = Wt [4096][2048] f16 (rows = out
// cols; rows [n0,n0+128) = nl tile, rows [n0+2048,...) = gate tile).
// t_next = g*t + (1-g)*relu(nl), g = sigmoid(gate).

__global__ __launch_bounds__(256, 2) void highway_kernel(
    const half_t* __restrict__ tin, const half_t* __restrict__ Wt,
    const float* __restrict__ bv, half_t* __restrict__ tout) {
  __shared__ half_t smA[128 * BK];
  __shared__ half_t smBn[128 * BK];
  __shared__ half_t smBg[128 * BK];
  const int tid = threadIdx.x;
  const int wave = tid >> 6, lane = tid & 63;
  const int l15 = lane & 15, l16 = lane >> 4;
  const int wr = wave >> 1, wc = wave & 1;
  const int m0 = blockIdx.y * 128, n0 = blockIdx.x * 128;

  const char* Ab  = (const char*)tin + (size_t)m0 * (TF * 2);
  const char* Bnb = (const char*)Wt + (size_t)n0 * (TF * 2);
  const char* Bgb = (const char*)Wt + (size_t)(n0 + TF) * (TF * 2);

  f32x4 accn[4][4] = {};
  f32x4 accg[4][4] = {};

  for (int kt = 0; kt < TF / BK; ++kt) {
    if (kt) __syncthreads();
    const int kb0 = kt * (BK * 2);     // byte offset of k-slice
#pragma unroll
    for (int i = 0; i < 4; ++i) {
      const int o = i * 4096 + tid * 16;         // linear byte in 16KB buffer
      const int row = o >> 7, kb = o & 127;      // [row][128B of k]
      const size_t gsrc = (size_t)row * (TF * 2) + kb0 + kb;
      gl_lds16(Ab + gsrc,  (char*)smA  + i * 4096 + wave * 1024);
      gl_lds16(Bnb + gsrc, (char*)smBn + i * 4096 + wave * 1024);
      gl_lds16(Bgb + gsrc, (char*)smBg + i * 4096 + wave * 1024);
    }
    __syncthreads();                   // drains vmcnt(0) before barrier
#pragma unroll
    for (int ks = 0; ks < 2; ++ks) {
      f16x8 af[4], bn_[4], bg_[4];
#pragma unroll
      for (int m = 0; m < 4; ++m) {
        const int row = wr * 64 + m * 16 + l15;
        af[m] = *(const f16x8*)((const char*)smA + row * 128 + ks * 64 + l16 * 16);
      }
#pragma unroll
      for (int n = 0; n < 4; ++n) {
        const int row = wc * 64 + n * 16 + l15;
        bn_[n] = *(const f16x8*)((const char*)smBn + row * 128 + ks * 64 + l16 * 16);
        bg_[n] = *(const f16x8*)((const char*)smBg + row * 128 + ks * 64 + l16 * 16);
      }
#pragma unroll
      for (int m = 0; m < 4; ++m)
#pragma unroll
        for (int n = 0; n < 4; ++n) {
          accn[m][n] = __builtin_amdgcn_mfma_f32_16x16x32_f16(af[m], bn_[n], accn[m][n], 0, 0, 0);
          accg[m][n] = __builtin_amdgcn_mfma_f32_16x16x32_f16(af[m], bg_[n], accg[m][n], 0, 0, 0);
        }
    }
  }

#pragma unroll
  for (int n = 0; n < 4; ++n) {
    const int gn = n0 + wc * 64 + n * 16 + l15;
    const float bnl = bv[gn];
    const float bgt = bv[TF + gn];
#pragma unroll
    for (int m = 0; m < 4; ++m) {
#pragma unroll
      for (int j = 0; j < 4; ++j) {
        const int gm = m0 + wr * 64 + m * 16 + l16 * 4 + j;  // C/D: col=l15, row=l16*4+j
        const float nl = accn[m][n][j] + bnl;
        const float gt = accg[m][n][j] + bgt;
        const float g = 1.f / (1.f + __expf(-gt));
        const float told = (float)tin[(size_t)gm * TF + gn];
        const float o = g * told + (1.f - g) * fmaxf(nl, 0.f);
        tout[(size_t)gm * TF + gn] = (half_t)o;
      }
    }
  }
}

// ---------------------------------------------------------------- proj ----

__global__ __launch_bounds__(256, 2) void proj_kernel(
    const half_t* __restrict__ tin, const half_t* __restrict__ Wt,
    const float* __restrict__ bv, float* __restrict__ out) {
  __shared__ half_t smA[128 * BK];
  __shared__ half_t smB[128 * BK];
  const int tid = threadIdx.x;
  const int wave = tid >> 6, lane = tid & 63;
  const int l15 = lane & 15, l16 = lane >> 4;
  const int wr = wave >> 1, wc = wave & 1;
  const int m0 = blockIdx.y * 128, n0 = blockIdx.x * 128;

  const char* Ab = (const char*)tin + (size_t)m0 * (TF * 2);
  const char* Bb = (const char*)Wt + (size_t)n0 * (TF * 2);

  f32x4 acc[4][4] = {};

  for (int kt = 0; kt < TF / BK; ++kt) {
    if (kt) __syncthreads();
    const int kb0 = kt * (BK * 2);
#pragma unroll
    for (int i = 0; i < 4; ++i) {
      const int o = i * 4096 + tid * 16;
      const int row = o >> 7, kb = o & 127;
      const size_t gsrc = (size_t)row * (TF * 2) + kb0 + kb;
      gl_lds16(Ab + gsrc, (char*)smA + i * 4096 + wave * 1024);
      gl_lds16(Bb + gsrc, (char*)smB + i * 4096 + wave * 1024);
    }
    __syncthreads();
#pragma unroll
    for (int ks = 0; ks < 2; ++ks) {
      f16x8 af[4], bf[4];
#pragma unroll
      for (int m = 0; m < 4; ++m) {
        const int row = wr * 64 + m * 16 + l15;
        af[m] = *(const f16x8*)((const char*)smA + row * 128 + ks * 64 + l16 * 16);
      }
#pragma unroll
      for (int n = 0; n < 4; ++n) {
        const int row = wc * 64 + n * 16 + l15;
        bf[n] = *(const f16x8*)((const char*)smB + row * 128 + ks * 64 + l16 * 16);
      }
#pragma unroll
      for (int m = 0; m < 4; ++m)
#pragma unroll
        for (int n = 0; n < 4; ++n)
          acc[m][n] = __builtin_amdgcn_mfma_f32_16x16x32_f16(af[m], bf[n], acc[m][n], 0, 0, 0);
    }
  }

#pragma unroll
  for (int n = 0; n < 4; ++n) {
    const int gn = n0 + wc * 64 + n * 16 + l15;
    const float bb = bv[gn];
#pragma unroll
    for (int m = 0; m < 4; ++m) {
#pragma unroll
      for (int j = 0; j < 4; ++j) {
        const int gm = m0 + wr * 64 + m * 16 + l16 * 4 + j;
        out[(size_t)gm * HID + gn] = acc[m][n][j] + bb;
      }
    }
  }
}

// -------------------------------------------------------------- launch ----

extern "C" void kernel_launch(void* const* d_in, const int* in_sizes, int n_in,
                              void* d_out, int out_size, void* d_ws, size_t ws_size,
                              hipStream_t stream) {
  const int*   ids  = (const int*)d_in[0];
  const float* cemb = (const float*)d_in[1];
  const float* cw[7]; const float* cb[7];
  for (int i = 0; i < 7; ++i) {
    cw[i] = (const float*)d_in[2 + 2 * i];
    cb[i] = (const float*)d_in[3 + 2 * i];
  }
  const float* hw_w0  = (const float*)d_in[16];
  const float* hw_b0  = (const float*)d_in[17];
  const float* hw_w1  = (const float*)d_in[18];
  const float* hw_b1  = (const float*)d_in[19];
  const float* proj_w = (const float*)d_in[20];
  const float* proj_b = (const float*)d_in[21];
  float* out = (float*)d_out;

  char* ws = (char*)d_ws;
  half_t* t0h  = (half_t*)(ws);
  half_t* t1h  = (half_t*)(ws + 16777216);
  half_t* wbuf = (half_t*)(ws + 33554432);   // reused: w0t -> w1t -> pwt

  // conv first, then weight transposes interleaved with GEMMs (same stream
  // => serialized => safe reuse of wbuf).
  conv_kernel<<<dim3(NTOK / TPB, 15), 256, 0, stream>>>(
      ids, cemb, cw[0], cb[0], cw[1], cb[1], cw[2], cb[2], cw[3], cb[3],
      cw[4], cb[4], cw[5], cb[5], cw[6], cb[6], t0h);

  tcvt_kernel<<<dim3(4096 / 64, TF / 64), 256, 0, stream>>>(hw_w0, wbuf, TF, 4096);
  highway_kernel<<<dim3(TF / 128, NTOK / 128), 256, 0, stream>>>(t0h, wbuf, hw_b0, t1h);

  tcvt_kernel<<<dim3(4096 / 64, TF / 64), 256, 0, stream>>>(hw_w1, wbuf, TF, 4096);
  highway_kernel<<<dim3(TF / 128, NTOK / 128), 256, 0, stream>>>(t1h, wbuf, hw_b1, t0h);

  tcvt_kernel<<<dim3(HID / 64, TF / 64), 256, 0, stream>>>(proj_w, wbuf, TF, HID);
  proj_kernel<<<dim3(HID / 128, NTOK / 128), 256, 0, stream>>>(t0h, wbuf, proj_b, out);
}

// Round 5
// 535.109 us; speedup vs baseline: 7.5528x; 7.5528x over previous
//
#include <hip/hip_runtime.h>
#include <math.h>

// CharacterBertCharacterCNN — Round 5 (resubmit of Round 4; GPU timeout, never ran)
// conv as f16 MFMA (shifted-A from LDS emb tile, packed weights, masked
// max-pool epilogue) -> t0h (f16); highway x2 + proj unchanged from Round 3
// (verified working: f16 MFMA, m97 structure).
//
// ws layout (bytes):
//   t0h      @ 0         : 4096*2048 f16 = 16,777,216
//   t1h      @ 16777216  : 16,777,216
//   wbuf     @ 33554432  : 16,777,216   (w0t, then w1t, then pwt)
//   bias_all @ 50331648  : 2048 f32 = 8,192
//   Wp       @ 50339840  : 219,136 f16 = 438,272
//   total ~50.8 MB

#define NTOK 4096
#define NCHAR 50
#define EMB 16
#define TF 2048
#define HID 768
#define BK 64       // GEMM k-tile

typedef float f32x4 __attribute__((ext_vector_type(4)));
typedef _Float16 f16x8 __attribute__((ext_vector_type(8)));
typedef _Float16 half_t;

__device__ __forceinline__ void gl_lds16(const void* g, void* l) {
  __builtin_amdgcn_global_load_lds(
      (const __attribute__((address_space(1))) void*)g,
      (__attribute__((address_space(3))) void*)l, 16, 0, 0);
}

// ------------------------------------------------------- weight packing ----
// Wp[width-major concat][c][k], k = j*16 + i (kpad per width), f16, zero pad.
// halfs offsets: W1@0(32x32) W2@1024(32x32) W3@2048(64x64) W4@6144(128x64)
// W5@14336(256x96) W6@38912(512x96) W7@88064(1024x128), total 219136.
__global__ __launch_bounds__(256) void wpack_kernel(
    const float* __restrict__ w0, const float* __restrict__ w1,
    const float* __restrict__ w2, const float* __restrict__ w3,
    const float* __restrict__ w4, const float* __restrict__ w5,
    const float* __restrict__ w6,
    const float* __restrict__ b0, const float* __restrict__ b1,
    const float* __restrict__ b2, const float* __restrict__ b3,
    const float* __restrict__ b4, const float* __restrict__ b5,
    const float* __restrict__ b6,
    half_t* __restrict__ Wp, float* __restrict__ bias_all) {
  const int idx = blockIdx.x * 256 + threadIdx.x;
  if (idx < 219136) {
    int c, k, w; const float* src;
    if (idx < 1024)       { c = idx >> 5;             k = idx & 31;          w = 1; src = w0; }
    else if (idx < 2048)  { const int t = idx - 1024;  c = t >> 5; k = t & 31;  w = 2; src = w1; }
    else if (idx < 6144)  { const int t = idx - 2048;  c = t >> 6; k = t & 63;  w = 3; src = w2; }
    else if (idx < 14336) { const int t = idx - 6144;  c = t >> 6; k = t & 63;  w = 4; src = w3; }
    else if (idx < 38912) { const int t = idx - 14336; c = t / 96; k = t % 96;  w = 5; src = w4; }
    else if (idx < 88064) { const int t = idx - 38912; c = t / 96; k = t % 96;  w = 6; src = w5; }
    else                  { const int t = idx - 88064; c = t >> 7; k = t & 127; w = 7; src = w6; }
    const int j = k >> 4, i = k & 15;
    Wp[idx] = (half_t)((j < w) ? src[(c * EMB + i) * w + j] : 0.f);
  } else if (idx < 219136 + 2048) {
    const int c = idx - 219136;
    float v;
    if (c < 32)        v = b0[c];
    else if (c < 64)   v = b1[c - 32];
    else if (c < 128)  v = b2[c - 64];
    else if (c < 256)  v = b3[c - 128];
    else if (c < 512)  v = b4[c - 256];
    else if (c < 1024) v = b5[c - 512];
    else               v = b6[c - 1024];
    bias_all[c] = v;
  }
}

// ---------------------------------------------------------------- conv ----
// Per wave: one token. emb tile f16 in LDS, 72 rows x 48B stride (rows >=50
// zeroed). A-frag(m,kk): lane l reads emb[(m*16 + (l&15)) + 2*kk + (l16>>1)]
// halfs [8*(l16&1) .. +8) — one ds_read_b128. B-frag: Wp[nt*16+l15][kk*32 +
// l16*8 ..+8) from global (L1-resident, shared by all waves). C/D row =
// l16*4+j = position; mask pos>=L with -inf, fmax + shfl_xor(16,32), bias,
// relu, store by lanes l16==0.

template<int MT, int KK>
__device__ __forceinline__ void conv_mfma_worker(
    const char* myemb, const half_t* __restrict__ Wp,
    const float* __restrict__ bias, half_t* __restrict__ outp,
    int nch, int kpad, int L, int lane) {
  const int l15 = lane & 15, l16 = lane >> 4;
  f16x8 a[MT][KK];
#pragma unroll
  for (int m = 0; m < MT; ++m)
#pragma unroll
    for (int kk = 0; kk < KK; ++kk) {
      const int row = m * 16 + l15 + 2 * kk + (l16 >> 1);
      a[m][kk] = *(const f16x8*)(myemb + row * 48 + (l16 & 1) * 16);
    }
  for (int nt = 0; nt < nch / 16; ++nt) {
    f16x8 b[KK];
#pragma unroll
    for (int kk = 0; kk < KK; ++kk)
      b[kk] = *(const f16x8*)&Wp[(size_t)(nt * 16 + l15) * kpad + kk * 32 + l16 * 8];
    f32x4 acc[MT];
#pragma unroll
    for (int m = 0; m < MT; ++m) acc[m] = (f32x4){0.f, 0.f, 0.f, 0.f};
#pragma unroll
    for (int kk = 0; kk < KK; ++kk)
#pragma unroll
      for (int m = 0; m < MT; ++m)
        acc[m] = __builtin_amdgcn_mfma_f32_16x16x32_f16(a[m][kk], b[kk], acc[m], 0, 0, 0);
    float v = -1e30f;
#pragma unroll
    for (int m = 0; m < MT; ++m)
#pragma unroll
      for (int j = 0; j < 4; ++j) {
        const int pos = m * 16 + l16 * 4 + j;
        v = (pos < L) ? fmaxf(v, acc[m][j]) : v;
      }
    v = fmaxf(v, __shfl_xor(v, 16));
    v = fmaxf(v, __shfl_xor(v, 32));
    if (l16 == 0) {
      const int c = nt * 16 + l15;
      outp[c] = (half_t)fmaxf(v + bias[c], 0.f);
    }
  }
}

__global__ __launch_bounds__(256) void conv_kernel(
    const int* __restrict__ ids, const float* __restrict__ cemb,
    const half_t* __restrict__ Wp, const float* __restrict__ bias_all,
    half_t* __restrict__ tout) {
  __shared__ char emb_s[4 * 72 * 48];
  const int tid = threadIdx.x, wave = tid >> 6, lane = tid & 63;
  const int tok = blockIdx.x * 4 + wave;
  char* myemb = emb_s + wave * (72 * 48);

  // stage: lane r handles row r (f32 gather -> f16), rows >= 50 zeroed.
  for (int r = lane; r < 72; r += 64) {
    f16x8 lo, hi;
#pragma unroll
    for (int q = 0; q < 8; ++q) { lo[q] = (half_t)0.f; hi[q] = (half_t)0.f; }
    if (r < NCHAR) {
      const int id = ids[tok * NCHAR + r];
      const float4 v0 = *(const float4*)&cemb[id * EMB + 0];
      const float4 v1 = *(const float4*)&cemb[id * EMB + 4];
      const float4 v2 = *(const float4*)&cemb[id * EMB + 8];
      const float4 v3 = *(const float4*)&cemb[id * EMB + 12];
      lo[0] = (half_t)v0.x; lo[1] = (half_t)v0.y; lo[2] = (half_t)v0.z; lo[3] = (half_t)v0.w;
      lo[4] = (half_t)v1.x; lo[5] = (half_t)v1.y; lo[6] = (half_t)v1.z; lo[7] = (half_t)v1.w;
      hi[0] = (half_t)v2.x; hi[1] = (half_t)v2.y; hi[2] = (half_t)v2.z; hi[3] = (half_t)v2.w;
      hi[4] = (half_t)v3.x; hi[5] = (half_t)v3.y; hi[6] = (half_t)v3.z; hi[7] = (half_t)v3.w;
    }
    *(f16x8*)(myemb + r * 48) = lo;
    *(f16x8*)(myemb + r * 48 + 16) = hi;
  }
  // no barrier: each wave reads only its own token's tile (same-wave
  // ds_write->ds_read ordering enforced by compiler lgkmcnt).

  half_t* outp = tout + (size_t)tok * TF;
  switch (blockIdx.y) {
    case 0:  conv_mfma_worker<4, 1>(myemb, Wp + 0,      bias_all + 0,    outp + 0,    32,  32,  50, lane); break;
    case 1:  conv_mfma_worker<4, 1>(myemb, Wp + 1024,   bias_all + 32,   outp + 32,   32,  32,  49, lane); break;
    case 2:  conv_mfma_worker<3, 2>(myemb, Wp + 2048,   bias_all + 64,   outp + 64,   64,  64,  48, lane); break;
    case 3:  conv_mfma_worker<3, 2>(myemb, Wp + 6144,   bias_all + 128,  outp + 128,  128, 64,  47, lane); break;
    case 4:  conv_mfma_worker<3, 3>(myemb, Wp + 14336,  bias_all + 256,  outp + 256,  256, 96,  46, lane); break;
    case 5:  conv_mfma_worker<3, 3>(myemb, Wp + 38912,  bias_all + 512,  outp + 512,  256, 96,  45, lane); break;
    case 6:  conv_mfma_worker<3, 3>(myemb, Wp + 63488,  bias_all + 768,  outp + 768,  256, 96,  45, lane); break;
    case 7:  conv_mfma_worker<3, 4>(myemb, Wp + 88064,  bias_all + 1024, outp + 1024, 256, 128, 44, lane); break;
    case 8:  conv_mfma_worker<3, 4>(myemb, Wp + 120832, bias_all + 1280, outp + 1280, 256, 128, 44, lane); break;
    case 9:  conv_mfma_worker<3, 4>(myemb, Wp + 153600, bias_all + 1536, outp + 1536, 256, 128, 44, lane); break;
    default: conv_mfma_worker<3, 4>(myemb, Wp + 186368, bias_all + 1792, outp + 1792, 256, 128, 44, lane); break;
  }
}

// ------------------------------------------------- transpose + f32->f16 ----
__global__ __launch_bounds__(256) void tcvt_kernel(
    const float* __restrict__ src, half_t* __restrict__ dst, int R, int C) {
  __shared__ half_t tile[64][72];
  const int tid = threadIdx.x;
  const int r0 = blockIdx.y * 64, c0 = blockIdx.x * 64;
  const int rr = tid >> 4, cq = tid & 15;
#pragma unroll
  for (int p = 0; p < 4; ++p) {
    const int r = rr + p * 16;
    const float4 v = *(const float4*)&src[(size_t)(r0 + r) * C + c0 + cq * 4];
    tile[cq * 4 + 0][r] = (half_t)v.x;
    tile[cq * 4 + 1][r] = (half_t)v.y;
    tile[cq * 4 + 2][r] = (half_t)v.z;
    tile[cq * 4 + 3][r] = (half_t)v.w;
  }
  __syncthreads();
#pragma unroll
  for (int p = 0; p < 2; ++p) {
    const int item = p * 256 + tid;
    const int c = item >> 3, ch = item & 7;
    const f16x8 v = *(const f16x8*)&tile[c][ch * 8];
    *(f16x8*)&dst[(size_t)(c0 + c) * R + r0 + ch * 8] = v;
  }
}

// ------------------------------------------------------------- highway ----
__global__ __launch_bounds__(256, 2) void highway_kernel(
    const half_t* __restrict__ tin, const half_t* __restrict__ Wt,
    const float* __restrict__ bv, half_t* __restrict__ tout) {
  __shared__ half_t smA[128 * BK];
  __shared__ half_t smBn[128 * BK];
  __shared__ half_t smBg[128 * BK];
  const int tid = threadIdx.x;
  const int wave = tid >> 6, lane = tid & 63;
  const int l15 = lane & 15, l16 = lane >> 4;
  const int wr = wave >> 1, wc = wave & 1;
  const int m0 = blockIdx.y * 128, n0 = blockIdx.x * 128;

  const char* Ab  = (const char*)tin + (size_t)m0 * (TF * 2);
  const char* Bnb = (const char*)Wt + (size_t)n0 * (TF * 2);
  const char* Bgb = (const char*)Wt + (size_t)(n0 + TF) * (TF * 2);

  f32x4 accn[4][4] = {};
  f32x4 accg[4][4] = {};

  for (int kt = 0; kt < TF / BK; ++kt) {
    if (kt) __syncthreads();
    const int kb0 = kt * (BK * 2);
#pragma unroll
    for (int i = 0; i < 4; ++i) {
      const int o = i * 4096 + tid * 16;
      const int row = o >> 7, kb = o & 127;
      const size_t gsrc = (size_t)row * (TF * 2) + kb0 + kb;
      gl_lds16(Ab + gsrc,  (char*)smA  + i * 4096 + wave * 1024);
      gl_lds16(Bnb + gsrc, (char*)smBn + i * 4096 + wave * 1024);
      gl_lds16(Bgb + gsrc, (char*)smBg + i * 4096 + wave * 1024);
    }
    __syncthreads();
#pragma unroll
    for (int ks = 0; ks < 2; ++ks) {
      f16x8 af[4], bn_[4], bg_[4];
#pragma unroll
      for (int m = 0; m < 4; ++m) {
        const int row = wr * 64 + m * 16 + l15;
        af[m] = *(const f16x8*)((const char*)smA + row * 128 + ks * 64 + l16 * 16);
      }
#pragma unroll
      for (int n = 0; n < 4; ++n) {
        const int row = wc * 64 + n * 16 + l15;
        bn_[n] = *(const f16x8*)((const char*)smBn + row * 128 + ks * 64 + l16 * 16);
        bg_[n] = *(const f16x8*)((const char*)smBg + row * 128 + ks * 64 + l16 * 16);
      }
#pragma unroll
      for (int m = 0; m < 4; ++m)
#pragma unroll
        for (int n = 0; n < 4; ++n) {
          accn[m][n] = __builtin_amdgcn_mfma_f32_16x16x32_f16(af[m], bn_[n], accn[m][n], 0, 0, 0);
          accg[m][n] = __builtin_amdgcn_mfma_f32_16x16x32_f16(af[m], bg_[n], accg[m][n], 0, 0, 0);
        }
    }
  }

#pragma unroll
  for (int n = 0; n < 4; ++n) {
    const int gn = n0 + wc * 64 + n * 16 + l15;
    const float bnl = bv[gn];
    const float bgt = bv[TF + gn];
#pragma unroll
    for (int m = 0; m < 4; ++m) {
#pragma unroll
      for (int j = 0; j < 4; ++j) {
        const int gm = m0 + wr * 64 + m * 16 + l16 * 4 + j;
        const float nl = accn[m][n][j] + bnl;
        const float gt = accg[m][n][j] + bgt;
        const float g = 1.f / (1.f + __expf(-gt));
        const float told = (float)tin[(size_t)gm * TF + gn];
        const float o = g * told + (1.f - g) * fmaxf(nl, 0.f);
        tout[(size_t)gm * TF + gn] = (half_t)o;
      }
    }
  }
}

// ---------------------------------------------------------------- proj ----
__global__ __launch_bounds__(256, 2) void proj_kernel(
    const half_t* __restrict__ tin, const half_t* __restrict__ Wt,
    const float* __restrict__ bv, float* __restrict__ out) {
  __shared__ half_t smA[128 * BK];
  __shared__ half_t smB[128 * BK];
  const int tid = threadIdx.x;
  const int wave = tid >> 6, lane = tid & 63;
  const int l15 = lane & 15, l16 = lane >> 4;
  const int wr = wave >> 1, wc = wave & 1;
  const int m0 = blockIdx.y * 128, n0 = blockIdx.x * 128;

  const char* Ab = (const char*)tin + (size_t)m0 * (TF * 2);
  const char* Bb = (const char*)Wt + (size_t)n0 * (TF * 2);

  f32x4 acc[4][4] = {};

  for (int kt = 0; kt < TF / BK; ++kt) {
    if (kt) __syncthreads();
    const int kb0 = kt * (BK * 2);
#pragma unroll
    for (int i = 0; i < 4; ++i) {
      const int o = i * 4096 + tid * 16;
      const int row = o >> 7, kb = o & 127;
      const size_t gsrc = (size_t)row * (TF * 2) + kb0 + kb;
      gl_lds16(Ab + gsrc, (char*)smA + i * 4096 + wave * 1024);
      gl_lds16(Bb + gsrc, (char*)smB + i * 4096 + wave * 1024);
    }
    __syncthreads();
#pragma unroll
    for (int ks = 0; ks < 2; ++ks) {
      f16x8 af[4], bf[4];
#pragma unroll
      for (int m = 0; m < 4; ++m) {
        const int row = wr * 64 + m * 16 + l15;
        af[m] = *(const f16x8*)((const char*)smA + row * 128 + ks * 64 + l16 * 16);
      }
#pragma unroll
      for (int n = 0; n < 4; ++n) {
        const int row = wc * 64 + n * 16 + l15;
        bf[n] = *(const f16x8*)((const char*)smB + row * 128 + ks * 64 + l16 * 16);
      }
#pragma unroll
      for (int m = 0; m < 4; ++m)
#pragma unroll
        for (int n = 0; n < 4; ++n)
          acc[m][n] = __builtin_amdgcn_mfma_f32_16x16x32_f16(af[m], bf[n], acc[m][n], 0, 0, 0);
    }
  }

#pragma unroll
  for (int n = 0; n < 4; ++n) {
    const int gn = n0 + wc * 64 + n * 16 + l15;
    const float bb = bv[gn];
#pragma unroll
    for (int m = 0; m < 4; ++m) {
#pragma unroll
      for (int j = 0; j < 4; ++j) {
        const int gm = m0 + wr * 64 + m * 16 + l16 * 4 + j;
        out[(size_t)gm * HID + gn] = acc[m][n][j] + bb;
      }
    }
  }
}

// -------------------------------------------------------------- launch ----
extern "C" void kernel_launch(void* const* d_in, const int* in_sizes, int n_in,
                              void* d_out, int out_size, void* d_ws, size_t ws_size,
                              hipStream_t stream) {
  const int*   ids  = (const int*)d_in[0];
  const float* cemb = (const float*)d_in[1];
  const float* cw[7]; const float* cb[7];
  for (int i = 0; i < 7; ++i) {
    cw[i] = (const float*)d_in[2 + 2 * i];
    cb[i] = (const float*)d_in[3 + 2 * i];
  }
  const float* hw_w0  = (const float*)d_in[16];
  const float* hw_b0  = (const float*)d_in[17];
  const float* hw_w1  = (const float*)d_in[18];
  const float* hw_b1  = (const float*)d_in[19];
  const float* proj_w = (const float*)d_in[20];
  const float* proj_b = (const float*)d_in[21];
  float* out = (float*)d_out;

  char* ws = (char*)d_ws;
  half_t* t0h      = (half_t*)(ws);
  half_t* t1h      = (half_t*)(ws + 16777216);
  half_t* wbuf     = (half_t*)(ws + 33554432);   // reused: w0t -> w1t -> pwt
  float*  bias_all = (float*)(ws + 50331648);
  half_t* Wp       = (half_t*)(ws + 50339840);

  wpack_kernel<<<864, 256, 0, stream>>>(
      cw[0], cw[1], cw[2], cw[3], cw[4], cw[5], cw[6],
      cb[0], cb[1], cb[2], cb[3], cb[4], cb[5], cb[6], Wp, bias_all);

  conv_kernel<<<dim3(NTOK / 4, 11), 256, 0, stream>>>(ids, cemb, Wp, bias_all, t0h);

  tcvt_kernel<<<dim3(4096 / 64, TF / 64), 256, 0, stream>>>(hw_w0, wbuf, TF, 4096);
  highway_kernel<<<dim3(TF / 128, NTOK / 128), 256, 0, stream>>>(t0h, wbuf, hw_b0, t1h);

  tcvt_kernel<<<dim3(4096 / 64, TF / 64), 256, 0, stream>>>(hw_w1, wbuf, TF, 4096);
  highway_kernel<<<dim3(TF / 128, NTOK / 128), 256, 0, stream>>>(t1h, wbuf, hw_b1, t0h);

  tcvt_kernel<<<dim3(HID / 64, TF / 64), 256, 0, stream>>>(proj_w, wbuf, TF, HID);
  proj_kernel<<<dim3(HID / 128, NTOK / 128), 256, 0, stream>>>(t0h, wbuf, proj_b, out);
}

// Round 6
// 527.449 us; speedup vs baseline: 7.6625x; 1.0145x over previous
//
#include <hip/hip_runtime.h>
#include <math.h>

// CharacterBertCharacterCNN — Round 6
// conv: MFMA with software-pipelined B-loads (double-buffered prefetch) and
// balanced slots (W1-W4 merged). GEMM chain (tcvt/highway/proj) byte-identical
// to Round 5 (verified: absmax 4.88e-4, ~307us).
//
// ws layout (bytes):
//   t0h      @ 0         : 4096*2048 f16 = 16,777,216
//   t1h      @ 16777216  : 16,777,216
//   wbuf     @ 33554432  : 16,777,216   (w0t, then w1t, then pwt)
//   bias_all @ 50331648  : 2048 f32 = 8,192
//   Wp       @ 50339840  : 219,136 f16 = 438,272
//   total ~50.8 MB

#define NTOK 4096
#define NCHAR 50
#define EMB 16
#define TF 2048
#define HID 768
#define BK 64       // GEMM k-tile

typedef float f32x4 __attribute__((ext_vector_type(4)));
typedef _Float16 f16x8 __attribute__((ext_vector_type(8)));
typedef _Float16 half_t;

__device__ __forceinline__ void gl_lds16(const void* g, void* l) {
  __builtin_amdgcn_global_load_lds(
      (const __attribute__((address_space(1))) void*)g,
      (__attribute__((address_space(3))) void*)l, 16, 0, 0);
}

// ------------------------------------------------------- weight packing ----
// Wp[width-major concat][c][k], k = j*16 + i (kpad per width), f16, zero pad.
// halfs offsets: W1@0(32x32) W2@1024(32x32) W3@2048(64x64) W4@6144(128x64)
// W5@14336(256x96) W6@38912(512x96) W7@88064(1024x128), total 219136.
__global__ __launch_bounds__(256) void wpack_kernel(
    const float* __restrict__ w0, const float* __restrict__ w1,
    const float* __restrict__ w2, const float* __restrict__ w3,
    const float* __restrict__ w4, const float* __restrict__ w5,
    const float* __restrict__ w6,
    const float* __restrict__ b0, const float* __restrict__ b1,
    const float* __restrict__ b2, const float* __restrict__ b3,
    const float* __restrict__ b4, const float* __restrict__ b5,
    const float* __restrict__ b6,
    half_t* __restrict__ Wp, float* __restrict__ bias_all) {
  const int idx = blockIdx.x * 256 + threadIdx.x;
  if (idx < 219136) {
    int c, k, w; const float* src;
    if (idx < 1024)       { c = idx >> 5;             k = idx & 31;          w = 1; src = w0; }
    else if (idx < 2048)  { const int t = idx - 1024;  c = t >> 5; k = t & 31;  w = 2; src = w1; }
    else if (idx < 6144)  { const int t = idx - 2048;  c = t >> 6; k = t & 63;  w = 3; src = w2; }
    else if (idx < 14336) { const int t = idx - 6144;  c = t >> 6; k = t & 63;  w = 4; src = w3; }
    else if (idx < 38912) { const int t = idx - 14336; c = t / 96; k = t % 96;  w = 5; src = w4; }
    else if (idx < 88064) { const int t = idx - 38912; c = t / 96; k = t % 96;  w = 6; src = w5; }
    else                  { const int t = idx - 88064; c = t >> 7; k = t & 127; w = 7; src = w6; }
    const int j = k >> 4, i = k & 15;
    Wp[idx] = (half_t)((j < w) ? src[(c * EMB + i) * w + j] : 0.f);
  } else if (idx < 219136 + 2048) {
    const int c = idx - 219136;
    float v;
    if (c < 32)        v = b0[c];
    else if (c < 64)   v = b1[c - 32];
    else if (c < 128)  v = b2[c - 64];
    else if (c < 256)  v = b3[c - 128];
    else if (c < 512)  v = b4[c - 256];
    else if (c < 1024) v = b5[c - 512];
    else               v = b6[c - 1024];
    bias_all[c] = v;
  }
}

// ---------------------------------------------------------------- conv ----
// Per wave: one token. emb tile f16 in LDS (72 rows x 48B, rows >=50 zero).
// A-frag(m,kk): lane l reads emb[m*16+(l&15) + 2*kk + (l16>>1)] halfs
// [8*(l16&1)..+8) — one ds_read_b128. B: Wp[nt*16+l15][kk*32+l16*8..+8)
// from global (L2-resident), DOUBLE-BUFFERED: prefetch nt+1 during nt's
// MFMAs so the ~200-300cy load latency overlaps compute. C/D row=l16*4+j=
// position; mask pos>=L, fmax + shfl_xor(16,32), bias, relu, store l16==0.

template<int MT, int KK>
__device__ __forceinline__ void conv_group(
    const f16x8 (&a)[MT][KK], const f16x8 (&b)[KK],
    const float* __restrict__ bias, half_t* __restrict__ outp,
    int nt, int L, int l15, int l16) {
  f32x4 acc[MT];
#pragma unroll
  for (int m = 0; m < MT; ++m) acc[m] = (f32x4){0.f, 0.f, 0.f, 0.f};
#pragma unroll
  for (int kk = 0; kk < KK; ++kk)
#pragma unroll
    for (int m = 0; m < MT; ++m)
      acc[m] = __builtin_amdgcn_mfma_f32_16x16x32_f16(a[m][kk], b[kk], acc[m], 0, 0, 0);
  float v = -1e30f;
#pragma unroll
  for (int m = 0; m < MT; ++m)
#pragma unroll
    for (int j = 0; j < 4; ++j) {
      const int pos = m * 16 + l16 * 4 + j;
      v = (pos < L) ? fmaxf(v, acc[m][j]) : v;
    }
  v = fmaxf(v, __shfl_xor(v, 16));
  v = fmaxf(v, __shfl_xor(v, 32));
  if (l16 == 0) {
    const int c = nt * 16 + l15;
    outp[c] = (half_t)fmaxf(v + bias[c], 0.f);
  }
}

template<int MT, int KK, int NT>   // NT even (2,4,8,16)
__device__ __forceinline__ void conv_mfma_worker(
    const char* myemb, const half_t* __restrict__ Wp,
    const float* __restrict__ bias, half_t* __restrict__ outp,
    int kpad, int L, int lane) {
  const int l15 = lane & 15, l16 = lane >> 4;
  f16x8 a[MT][KK];
#pragma unroll
  for (int m = 0; m < MT; ++m)
#pragma unroll
    for (int kk = 0; kk < KK; ++kk) {
      const int row = m * 16 + l15 + 2 * kk + (l16 >> 1);
      a[m][kk] = *(const f16x8*)(myemb + row * 48 + (l16 & 1) * 16);
    }
  const half_t* bp = Wp + (size_t)l15 * kpad + l16 * 8;
  const size_t ntstep = (size_t)16 * kpad;   // halfs per nt group
  f16x8 b0[KK], b1[KK];
#pragma unroll
  for (int kk = 0; kk < KK; ++kk) b0[kk] = *(const f16x8*)(bp + kk * 32);
#pragma unroll
  for (int nt = 0; nt < NT; nt += 2) {
    // prefetch nt+1 into b1 before computing nt
#pragma unroll
    for (int kk = 0; kk < KK; ++kk)
      b1[kk] = *(const f16x8*)(bp + (size_t)(nt + 1) * ntstep + kk * 32);
    conv_group<MT, KK>(a, b0, bias, outp, nt, L, l15, l16);
    if (nt + 2 < NT) {
      // prefetch nt+2 into b0 before computing nt+1
#pragma unroll
      for (int kk = 0; kk < KK; ++kk)
        b0[kk] = *(const f16x8*)(bp + (size_t)(nt + 2) * ntstep + kk * 32);
    }
    conv_group<MT, KK>(a, b1, bias, outp, nt + 1, L, l15, l16);
  }
}

// 8 balanced slots (MFMAs/token): 0:{W1,W2,W3,W4}=88  1:{W5}=144
// 2,3:{W6 halves}=144  4-7:{W7 quarters}=192
__global__ __launch_bounds__(256) void conv_kernel(
    const int* __restrict__ ids, const float* __restrict__ cemb,
    const half_t* __restrict__ Wp, const float* __restrict__ bias_all,
    half_t* __restrict__ tout) {
  __shared__ char emb_s[4 * 72 * 48];
  const int tid = threadIdx.x, wave = tid >> 6, lane = tid & 63;
  const int tok = blockIdx.x * 4 + wave;
  char* myemb = emb_s + wave * (72 * 48);

  // stage: lane r handles row r (f32 gather -> f16), rows >= 50 zeroed.
  for (int r = lane; r < 72; r += 64) {
    f16x8 lo, hi;
#pragma unroll
    for (int q = 0; q < 8; ++q) { lo[q] = (half_t)0.f; hi[q] = (half_t)0.f; }
    if (r < NCHAR) {
      const int id = ids[tok * NCHAR + r];
      const float4 v0 = *(const float4*)&cemb[id * EMB + 0];
      const float4 v1 = *(const float4*)&cemb[id * EMB + 4];
      const float4 v2 = *(const float4*)&cemb[id * EMB + 8];
      const float4 v3 = *(const float4*)&cemb[id * EMB + 12];
      lo[0] = (half_t)v0.x; lo[1] = (half_t)v0.y; lo[2] = (half_t)v0.z; lo[3] = (half_t)v0.w;
      lo[4] = (half_t)v1.x; lo[5] = (half_t)v1.y; lo[6] = (half_t)v1.z; lo[7] = (half_t)v1.w;
      hi[0] = (half_t)v2.x; hi[1] = (half_t)v2.y; hi[2] = (half_t)v2.z; hi[3] = (half_t)v2.w;
      hi[4] = (half_t)v3.x; hi[5] = (half_t)v3.y; hi[6] = (half_t)v3.z; hi[7] = (half_t)v3.w;
    }
    *(f16x8*)(myemb + r * 48) = lo;
    *(f16x8*)(myemb + r * 48 + 16) = hi;
  }
  // no barrier: each wave reads only its own token's tile (same-wave
  // ds_write->ds_read ordering enforced by compiler lgkmcnt).

  half_t* outp = tout + (size_t)tok * TF;
  switch (blockIdx.y) {
    case 0:
      conv_mfma_worker<4, 1, 2>(myemb, Wp + 0,    bias_all + 0,   outp + 0,   32, 50, lane);
      conv_mfma_worker<4, 1, 2>(myemb, Wp + 1024, bias_all + 32,  outp + 32,  32, 49, lane);
      conv_mfma_worker<3, 2, 4>(myemb, Wp + 2048, bias_all + 64,  outp + 64,  64, 48, lane);
      conv_mfma_worker<3, 2, 8>(myemb, Wp + 6144, bias_all + 128, outp + 128, 64, 47, lane);
      break;
    case 1:  conv_mfma_worker<3, 3, 16>(myemb, Wp + 14336,  bias_all + 256,  outp + 256,  96,  46, lane); break;
    case 2:  conv_mfma_worker<3, 3, 16>(myemb, Wp + 38912,  bias_all + 512,  outp + 512,  96,  45, lane); break;
    case 3:  conv_mfma_worker<3, 3, 16>(myemb, Wp + 63488,  bias_all + 768,  outp + 768,  96,  45, lane); break;
    case 4:  conv_mfma_worker<3, 4, 16>(myemb, Wp + 88064,  bias_all + 1024, outp + 1024, 128, 44, lane); break;
    case 5:  conv_mfma_worker<3, 4, 16>(myemb, Wp + 120832, bias_all + 1280, outp + 1280, 128, 44, lane); break;
    case 6:  conv_mfma_worker<3, 4, 16>(myemb, Wp + 153600, bias_all + 1536, outp + 1536, 128, 44, lane); break;
    default: conv_mfma_worker<3, 4, 16>(myemb, Wp + 186368, bias_all + 1792, outp + 1792, 128, 44, lane); break;
  }
}

// ------------------------------------------------- transpose + f32->f16 ----
__global__ __launch_bounds__(256) void tcvt_kernel(
    const float* __restrict__ src, half_t* __restrict__ dst, int R, int C) {
  __shared__ half_t tile[64][72];
  const int tid = threadIdx.x;
  const int r0 = blockIdx.y * 64, c0 = blockIdx.x * 64;
  const int rr = tid >> 4, cq = tid & 15;
#pragma unroll
  for (int p = 0; p < 4; ++p) {
    const int r = rr + p * 16;
    const float4 v = *(const float4*)&src[(size_t)(r0 + r) * C + c0 + cq * 4];
    tile[cq * 4 + 0][r] = (half_t)v.x;
    tile[cq * 4 + 1][r] = (half_t)v.y;
    tile[cq * 4 + 2][r] = (half_t)v.z;
    tile[cq * 4 + 3][r] = (half_t)v.w;
  }
  __syncthreads();
#pragma unroll
  for (int p = 0; p < 2; ++p) {
    const int item = p * 256 + tid;
    const int c = item >> 3, ch = item & 7;
    const f16x8 v = *(const f16x8*)&tile[c][ch * 8];
    *(f16x8*)&dst[(size_t)(c0 + c) * R + r0 + ch * 8] = v;
  }
}

// ------------------------------------------------------------- highway ----
__global__ __launch_bounds__(256, 2) void highway_kernel(
    const half_t* __restrict__ tin, const half_t* __restrict__ Wt,
    const float* __restrict__ bv, half_t* __restrict__ tout) {
  __shared__ half_t smA[128 * BK];
  __shared__ half_t smBn[128 * BK];
  __shared__ half_t smBg[128 * BK];
  const int tid = threadIdx.x;
  const int wave = tid >> 6, lane = tid & 63;
  const int l15 = lane & 15, l16 = lane >> 4;
  const int wr = wave >> 1, wc = wave & 1;
  const int m0 = blockIdx.y * 128, n0 = blockIdx.x * 128;

  const char* Ab  = (const char*)tin + (size_t)m0 * (TF * 2);
  const char* Bnb = (const char*)Wt + (size_t)n0 * (TF * 2);
  const char* Bgb = (const char*)Wt + (size_t)(n0 + TF) * (TF * 2);

  f32x4 accn[4][4] = {};
  f32x4 accg[4][4] = {};

  for (int kt = 0; kt < TF / BK; ++kt) {
    if (kt) __syncthreads();
    const int kb0 = kt * (BK * 2);
#pragma unroll
    for (int i = 0; i < 4; ++i) {
      const int o = i * 4096 + tid * 16;
      const int row = o >> 7, kb = o & 127;
      const size_t gsrc = (size_t)row * (TF * 2) + kb0 + kb;
      gl_lds16(Ab + gsrc,  (char*)smA  + i * 4096 + wave * 1024);
      gl_lds16(Bnb + gsrc, (char*)smBn + i * 4096 + wave * 1024);
      gl_lds16(Bgb + gsrc, (char*)smBg + i * 4096 + wave * 1024);
    }
    __syncthreads();
#pragma unroll
    for (int ks = 0; ks < 2; ++ks) {
      f16x8 af[4], bn_[4], bg_[4];
#pragma unroll
      for (int m = 0; m < 4; ++m) {
        const int row = wr * 64 + m * 16 + l15;
        af[m] = *(const f16x8*)((const char*)smA + row * 128 + ks * 64 + l16 * 16);
      }
#pragma unroll
      for (int n = 0; n < 4; ++n) {
        const int row = wc * 64 + n * 16 + l15;
        bn_[n] = *(const f16x8*)((const char*)smBn + row * 128 + ks * 64 + l16 * 16);
        bg_[n] = *(const f16x8*)((const char*)smBg + row * 128 + ks * 64 + l16 * 16);
      }
#pragma unroll
      for (int m = 0; m < 4; ++m)
#pragma unroll
        for (int n = 0; n < 4; ++n) {
          accn[m][n] = __builtin_amdgcn_mfma_f32_16x16x32_f16(af[m], bn_[n], accn[m][n], 0, 0, 0);
          accg[m][n] = __builtin_amdgcn_mfma_f32_16x16x32_f16(af[m], bg_[n], accg[m][n], 0, 0, 0);
        }
    }
  }

#pragma unroll
  for (int n = 0; n < 4; ++n) {
    const int gn = n0 + wc * 64 + n * 16 + l15;
    const float bnl = bv[gn];
    const float bgt = bv[TF + gn];
#pragma unroll
    for (int m = 0; m < 4; ++m) {
#pragma unroll
      for (int j = 0; j < 4; ++j) {
        const int gm = m0 + wr * 64 + m * 16 + l16 * 4 + j;
        const float nl = accn[m][n][j] + bnl;
        const float gt = accg[m][n][j] + bgt;
        const float g = 1.f / (1.f + __expf(-gt));
        const float told = (float)tin[(size_t)gm * TF + gn];
        const float o = g * told + (1.f - g) * fmaxf(nl, 0.f);
        tout[(size_t)gm * TF + gn] = (half_t)o;
      }
    }
  }
}

// ---------------------------------------------------------------- proj ----
__global__ __launch_bounds__(256, 2) void proj_kernel(
    const half_t* __restrict__ tin, const half_t* __restrict__ Wt,
    const float* __restrict__ bv, float* __restrict__ out) {
  __shared__ half_t smA[128 * BK];
  __shared__ half_t smB[128 * BK];
  const int tid = threadIdx.x;
  const int wave = tid >> 6, lane = tid & 63;
  const int l15 = lane & 15, l16 = lane >> 4;
  const int wr = wave >> 1, wc = wave & 1;
  const int m0 = blockIdx.y * 128, n0 = blockIdx.x * 128;

  const char* Ab = (const char*)tin + (size_t)m0 * (TF * 2);
  const char* Bb = (const char*)Wt + (size_t)n0 * (TF * 2);

  f32x4 acc[4][4] = {};

  for (int kt = 0; kt < TF / BK; ++kt) {
    if (kt) __syncthreads();
    const int kb0 = kt * (BK * 2);
#pragma unroll
    for (int i = 0; i < 4; ++i) {
      const int o = i * 4096 + tid * 16;
      const int row = o >> 7, kb = o & 127;
      const size_t gsrc = (size_t)row * (TF * 2) + kb0 + kb;
      gl_lds16(Ab + gsrc, (char*)smA + i * 4096 + wave * 1024);
      gl_lds16(Bb + gsrc, (char*)smB + i * 4096 + wave * 1024);
    }
    __syncthreads();
#pragma unroll
    for (int ks = 0; ks < 2; ++ks) {
      f16x8 af[4], bf[4];
#pragma unroll
      for (int m = 0; m < 4; ++m) {
        const int row = wr * 64 + m * 16 + l15;
        af[m] = *(const f16x8*)((const char*)smA + row * 128 + ks * 64 + l16 * 16);
      }
#pragma unroll
      for (int n = 0; n < 4; ++n) {
        const int row = wc * 64 + n * 16 + l15;
        bf[n] = *(const f16x8*)((const char*)smB + row * 128 + ks * 64 + l16 * 16);
      }
#pragma unroll
      for (int m = 0; m < 4; ++m)
#pragma unroll
        for (int n = 0; n < 4; ++n)
          acc[m][n] = __builtin_amdgcn_mfma_f32_16x16x32_f16(af[m], bf[n], acc[m][n], 0, 0, 0);
    }
  }

#pragma unroll
  for (int n = 0; n < 4; ++n) {
    const int gn = n0 + wc * 64 + n * 16 + l15;
    const float bb = bv[gn];
#pragma unroll
    for (int m = 0; m < 4; ++m) {
#pragma unroll
      for (int j = 0; j < 4; ++j) {
        const int gm = m0 + wr * 64 + m * 16 + l16 * 4 + j;
        out[(size_t)gm * HID + gn] = acc[m][n][j] + bb;
      }
    }
  }
}

// -------------------------------------------------------------- launch ----
extern "C" void kernel_launch(void* const* d_in, const int* in_sizes, int n_in,
                              void* d_out, int out_size, void* d_ws, size_t ws_size,
                              hipStream_t stream) {
  const int*   ids  = (const int*)d_in[0];
  const float* cemb = (const float*)d_in[1];
  const float* cw[7]; const float* cb[7];
  for (int i = 0; i < 7; ++i) {
    cw[i] = (const float*)d_in[2 + 2 * i];
    cb[i] = (const float*)d_in[3 + 2 * i];
  }
  const float* hw_w0  = (const float*)d_in[16];
  const float* hw_b0  = (const float*)d_in[17];
  const float* hw_w1  = (const float*)d_in[18];
  const float* hw_b1  = (const float*)d_in[19];
  const float* proj_w = (const float*)d_in[20];
  const float* proj_b = (const float*)d_in[21];
  float* out = (float*)d_out;

  char* ws = (char*)d_ws;
  half_t* t0h      = (half_t*)(ws);
  half_t* t1h      = (half_t*)(ws + 16777216);
  half_t* wbuf     = (half_t*)(ws + 33554432);   // reused: w0t -> w1t -> pwt
  float*  bias_all = (float*)(ws + 50331648);
  half_t* Wp       = (half_t*)(ws + 50339840);

  wpack_kernel<<<864, 256, 0, stream>>>(
      cw[0], cw[1], cw[2], cw[3], cw[4], cw[5], cw[6],
      cb[0], cb[1], cb[2], cb[3], cb[4], cb[5], cb[6], Wp, bias_all);

  conv_kernel<<<dim3(NTOK / 4, 8), 256, 0, stream>>>(ids, cemb, Wp, bias_all, t0h);

  tcvt_kernel<<<dim3(4096 / 64, TF / 64), 256, 0, stream>>>(hw_w0, wbuf, TF, 4096);
  highway_kernel<<<dim3(TF / 128, NTOK / 128), 256, 0, stream>>>(t0h, wbuf, hw_b0, t1h);

  tcvt_kernel<<<dim3(4096 / 64, TF / 64), 256, 0, stream>>>(hw_w1, wbuf, TF, 4096);
  highway_kernel<<<dim3(TF / 128, NTOK / 128), 256, 0, stream>>>(t1h, wbuf, hw_b1, t0h);

  tcvt_kernel<<<dim3(HID / 64, TF / 64), 256, 0, stream>>>(proj_w, wbuf, TF, HID);
  proj_kernel<<<dim3(HID / 128, NTOK / 128), 256, 0, stream>>>(t0h, wbuf, proj_b, out);
}

// Round 7
// 515.944 us; speedup vs baseline: 7.8334x; 1.0223x over previous
//
#include <hip/hip_runtime.h>
#include <math.h>

// CharacterBertCharacterCNN — Round 7
// conv: MFMA, __launch_bounds__(256,4) so A-frags + B-dbuf stay in VGPRs
// (R6's default choice of 56 VGPR rematerialized A from LDS and collapsed
// the prefetch), tree-max epilogue with LDS-deferred cross-lane reduce
// (replaces 2 serial shfl_xor per nt-group). GEMM chain byte-identical to
// Round 5/6 (verified absmax 4.88e-4).
//
// ws layout (bytes):
//   t0h      @ 0         : 4096*2048 f16 = 16,777,216
//   t1h      @ 16777216  : 16,777,216
//   wbuf     @ 33554432  : 16,777,216   (w0t, then w1t, then pwt)
//   bias_all @ 50331648  : 2048 f32 = 8,192
//   Wp       @ 50339840  : 219,136 f16 = 438,272
//   total ~50.8 MB

#define NTOK 4096
#define NCHAR 50
#define EMB 16
#define TF 2048
#define HID 768
#define BK 64       // GEMM k-tile

typedef float f32x4 __attribute__((ext_vector_type(4)));
typedef _Float16 f16x8 __attribute__((ext_vector_type(8)));
typedef _Float16 half_t;

__device__ __forceinline__ void gl_lds16(const void* g, void* l) {
  __builtin_amdgcn_global_load_lds(
      (const __attribute__((address_space(1))) void*)g,
      (__attribute__((address_space(3))) void*)l, 16, 0, 0);
}

// ------------------------------------------------------- weight packing ----
// Wp[width-major concat][c][k], k = j*16 + i (kpad per width), f16, zero pad.
// halfs offsets: W1@0(32x32) W2@1024(32x32) W3@2048(64x64) W4@6144(128x64)
// W5@14336(256x96) W6@38912(512x96) W7@88064(1024x128), total 219136.
__global__ __launch_bounds__(256) void wpack_kernel(
    const float* __restrict__ w0, const float* __restrict__ w1,
    const float* __restrict__ w2, const float* __restrict__ w3,
    const float* __restrict__ w4, const float* __restrict__ w5,
    const float* __restrict__ w6,
    const float* __restrict__ b0, const float* __restrict__ b1,
    const float* __restrict__ b2, const float* __restrict__ b3,
    const float* __restrict__ b4, const float* __restrict__ b5,
    const float* __restrict__ b6,
    half_t* __restrict__ Wp, float* __restrict__ bias_all) {
  const int idx = blockIdx.x * 256 + threadIdx.x;
  if (idx < 219136) {
    int c, k, w; const float* src;
    if (idx < 1024)       { c = idx >> 5;             k = idx & 31;          w = 1; src = w0; }
    else if (idx < 2048)  { const int t = idx - 1024;  c = t >> 5; k = t & 31;  w = 2; src = w1; }
    else if (idx < 6144)  { const int t = idx - 2048;  c = t >> 6; k = t & 63;  w = 3; src = w2; }
    else if (idx < 14336) { const int t = idx - 6144;  c = t >> 6; k = t & 63;  w = 4; src = w3; }
    else if (idx < 38912) { const int t = idx - 14336; c = t / 96; k = t % 96;  w = 5; src = w4; }
    else if (idx < 88064) { const int t = idx - 38912; c = t / 96; k = t % 96;  w = 6; src = w5; }
    else                  { const int t = idx - 88064; c = t >> 7; k = t & 127; w = 7; src = w6; }
    const int j = k >> 4, i = k & 15;
    Wp[idx] = (half_t)((j < w) ? src[(c * EMB + i) * w + j] : 0.f);
  } else if (idx < 219136 + 2048) {
    const int c = idx - 219136;
    float v;
    if (c < 32)        v = b0[c];
    else if (c < 64)   v = b1[c - 32];
    else if (c < 128)  v = b2[c - 64];
    else if (c < 256)  v = b3[c - 128];
    else if (c < 512)  v = b4[c - 256];
    else if (c < 1024) v = b5[c - 512];
    else               v = b6[c - 1024];
    bias_all[c] = v;
  }
}

// ---------------------------------------------------------------- conv ----
// Per wave: one token. emb tile f16 in LDS (72 rows x 48B, rows >=50 zero).
// A-frag(m,kk): lane l reads emb[m*16+(l&15) + 2*kk + (l16>>1)] halfs
// [8*(l16&1)..+8). B double-buffered from global (L2-resident). Epilogue:
// compile-time-masked TREE max of the lane's MT*4 positions, one ds_write
// into pm[l16][nt*16+l15] (stride NT*16+8 -> 2-way banks, free); after the
// nt-loop a batched reduce over the 4 row-group partials, coalesced store.

template<int MT, int KK, int NT, int L>
__device__ __forceinline__ void conv_mfma_worker(
    const char* myemb, float* pm,            // this wave's [4][NT*16+8] region
    const half_t* __restrict__ Wp, const float* __restrict__ bias,
    half_t* __restrict__ outp, int kpad, int lane) {
  constexpr int S = NT * 16 + 8;
  const int l15 = lane & 15, l16 = lane >> 4;

  f16x8 a[MT][KK];
#pragma unroll
  for (int m = 0; m < MT; ++m)
#pragma unroll
    for (int kk = 0; kk < KK; ++kk) {
      const int row = m * 16 + l15 + 2 * kk + (l16 >> 1);
      a[m][kk] = *(const f16x8*)(myemb + row * 48 + (l16 & 1) * 16);
    }

  const half_t* bp = Wp + (size_t)l15 * kpad + l16 * 8;
  const size_t ntstep = (size_t)16 * kpad;

  auto group = [&](int nt, const f16x8 (&b)[KK]) {
    f32x4 acc[MT];
#pragma unroll
    for (int m = 0; m < MT; ++m) acc[m] = (f32x4){0.f, 0.f, 0.f, 0.f};
#pragma unroll
    for (int kk = 0; kk < KK; ++kk)
#pragma unroll
      for (int m = 0; m < MT; ++m)
        acc[m] = __builtin_amdgcn_mfma_f32_16x16x32_f16(a[m][kk], b[kk], acc[m], 0, 0, 0);
    float t[MT * 4];
#pragma unroll
    for (int m = 0; m < MT; ++m)
#pragma unroll
      for (int j = 0; j < 4; ++j) {
        if constexpr (true) {
          const int pos = m * 16 + l16 * 4 + j;  // l16 runtime, rest static
          if ((m * 16 + 15) < L)                 // compile-time: whole tile valid
            t[m * 4 + j] = acc[m][j];
          else
            t[m * 4 + j] = (pos < L) ? acc[m][j] : -1e30f;
        }
      }
#pragma unroll
    for (int s = 1; s < MT * 4; s *= 2)
#pragma unroll
      for (int i = 0; i + s < MT * 4; i += 2 * s)
        t[i] = fmaxf(t[i], t[i + s]);
    pm[l16 * S + nt * 16 + l15] = t[0];
  };

  f16x8 b0[KK], b1[KK];
#pragma unroll
  for (int kk = 0; kk < KK; ++kk) b0[kk] = *(const f16x8*)(bp + kk * 32);
#pragma unroll
  for (int nt = 0; nt < NT; nt += 2) {
#pragma unroll
    for (int kk = 0; kk < KK; ++kk)
      b1[kk] = *(const f16x8*)(bp + (size_t)(nt + 1) * ntstep + kk * 32);
    group(nt, b0);
    if (nt + 2 < NT) {
#pragma unroll
      for (int kk = 0; kk < KK; ++kk)
        b0[kk] = *(const f16x8*)(bp + (size_t)(nt + 2) * ntstep + kk * 32);
    }
    group(nt + 1, b1);
  }

  // batched cross-row-group reduce (compiler orders LDS ops within the wave)
#pragma unroll
  for (int c0 = 0; c0 < NT * 16; c0 += 64) {
    const int c = c0 + lane;
    if (c < NT * 16) {
      const float v0 = pm[0 * S + c], v1 = pm[1 * S + c];
      const float v2 = pm[2 * S + c], v3 = pm[3 * S + c];
      const float mx = fmaxf(fmaxf(v0, v1), fmaxf(v2, v3));
      outp[c] = (half_t)fmaxf(mx + bias[c], 0.f);
    }
  }
}

// 8 balanced slots (MFMAs/token): 0:{W1,W2,W3,W4}=88  1:{W5}=144
// 2,3:{W6 halves}=144  4-7:{W7 quarters}=192
__global__ __launch_bounds__(256, 4) void conv_kernel(
    const int* __restrict__ ids, const float* __restrict__ cemb,
    const half_t* __restrict__ Wp, const float* __restrict__ bias_all,
    half_t* __restrict__ tout) {
  __shared__ char emb_s[4 * 72 * 48];        // 13824 B
  __shared__ float pmax_s[4 * 4 * 264];      // 16896 B: per wave [4][264]
  const int tid = threadIdx.x, wave = tid >> 6, lane = tid & 63;
  const int tok = blockIdx.x * 4 + wave;
  char* myemb = emb_s + wave * (72 * 48);
  float* pm = pmax_s + wave * (4 * 264);

  // stage: lane r handles row r (f32 gather -> f16), rows >= 50 zeroed.
  for (int r = lane; r < 72; r += 64) {
    f16x8 lo, hi;
#pragma unroll
    for (int q = 0; q < 8; ++q) { lo[q] = (half_t)0.f; hi[q] = (half_t)0.f; }
    if (r < NCHAR) {
      const int id = ids[tok * NCHAR + r];
      const float4 v0 = *(const float4*)&cemb[id * EMB + 0];
      const float4 v1 = *(const float4*)&cemb[id * EMB + 4];
      const float4 v2 = *(const float4*)&cemb[id * EMB + 8];
      const float4 v3 = *(const float4*)&cemb[id * EMB + 12];
      lo[0] = (half_t)v0.x; lo[1] = (half_t)v0.y; lo[2] = (half_t)v0.z; lo[3] = (half_t)v0.w;
      lo[4] = (half_t)v1.x; lo[5] = (half_t)v1.y; lo[6] = (half_t)v1.z; lo[7] = (half_t)v1.w;
      hi[0] = (half_t)v2.x; hi[1] = (half_t)v2.y; hi[2] = (half_t)v2.z; hi[3] = (half_t)v2.w;
      hi[4] = (half_t)v3.x; hi[5] = (half_t)v3.y; hi[6] = (half_t)v3.z; hi[7] = (half_t)v3.w;
    }
    *(f16x8*)(myemb + r * 48) = lo;
    *(f16x8*)(myemb + r * 48 + 16) = hi;
  }
  // no barrier: each wave reads only its own token's tile (same-wave
  // ds_write->ds_read ordering enforced by compiler lgkmcnt).

  half_t* outp = tout + (size_t)tok * TF;
  switch (blockIdx.y) {
    case 0:
      conv_mfma_worker<4, 1, 2, 50>(myemb, pm, Wp + 0,    bias_all + 0,   outp + 0,   32, lane);
      conv_mfma_worker<4, 1, 2, 49>(myemb, pm, Wp + 1024, bias_all + 32,  outp + 32,  32, lane);
      conv_mfma_worker<3, 2, 4, 48>(myemb, pm, Wp + 2048, bias_all + 64,  outp + 64,  64, lane);
      conv_mfma_worker<3, 2, 8, 47>(myemb, pm, Wp + 6144, bias_all + 128, outp + 128, 64, lane);
      break;
    case 1:  conv_mfma_worker<3, 3, 16, 46>(myemb, pm, Wp + 14336,  bias_all + 256,  outp + 256,  96,  lane); break;
    case 2:  conv_mfma_worker<3, 3, 16, 45>(myemb, pm, Wp + 38912,  bias_all + 512,  outp + 512,  96,  lane); break;
    case 3:  conv_mfma_worker<3, 3, 16, 45>(myemb, pm, Wp + 63488,  bias_all + 768,  outp + 768,  96,  lane); break;
    case 4:  conv_mfma_worker<3, 4, 16, 44>(myemb, pm, Wp + 88064,  bias_all + 1024, outp + 1024, 128, lane); break;
    case 5:  conv_mfma_worker<3, 4, 16, 44>(myemb, pm, Wp + 120832, bias_all + 1280, outp + 1280, 128, lane); break;
    case 6:  conv_mfma_worker<3, 4, 16, 44>(myemb, pm, Wp + 153600, bias_all + 1536, outp + 1536, 128, lane); break;
    default: conv_mfma_worker<3, 4, 16, 44>(myemb, pm, Wp + 186368, bias_all + 1792, outp + 1792, 128, lane); break;
  }
}

// ------------------------------------------------- transpose + f32->f16 ----
__global__ __launch_bounds__(256) void tcvt_kernel(
    const float* __restrict__ src, half_t* __restrict__ dst, int R, int C) {
  __shared__ half_t tile[64][72];
  const int tid = threadIdx.x;
  const int r0 = blockIdx.y * 64, c0 = blockIdx.x * 64;
  const int rr = tid >> 4, cq = tid & 15;
#pragma unroll
  for (int p = 0; p < 4; ++p) {
    const int r = rr + p * 16;
    const float4 v = *(const float4*)&src[(size_t)(r0 + r) * C + c0 + cq * 4];
    tile[cq * 4 + 0][r] = (half_t)v.x;
    tile[cq * 4 + 1][r] = (half_t)v.y;
    tile[cq * 4 + 2][r] = (half_t)v.z;
    tile[cq * 4 + 3][r] = (half_t)v.w;
  }
  __syncthreads();
#pragma unroll
  for (int p = 0; p < 2; ++p) {
    const int item = p * 256 + tid;
    const int c = item >> 3, ch = item & 7;
    const f16x8 v = *(const f16x8*)&tile[c][ch * 8];
    *(f16x8*)&dst[(size_t)(c0 + c) * R + r0 + ch * 8] = v;
  }
}

// ------------------------------------------------------------- highway ----
__global__ __launch_bounds__(256, 2) void highway_kernel(
    const half_t* __restrict__ tin, const half_t* __restrict__ Wt,
    const float* __restrict__ bv, half_t* __restrict__ tout) {
  __shared__ half_t smA[128 * BK];
  __shared__ half_t smBn[128 * BK];
  __shared__ half_t smBg[128 * BK];
  const int tid = threadIdx.x;
  const int wave = tid >> 6, lane = tid & 63;
  const int l15 = lane & 15, l16 = lane >> 4;
  const int wr = wave >> 1, wc = wave & 1;
  const int m0 = blockIdx.y * 128, n0 = blockIdx.x * 128;

  const char* Ab  = (const char*)tin + (size_t)m0 * (TF * 2);
  const char* Bnb = (const char*)Wt + (size_t)n0 * (TF * 2);
  const char* Bgb = (const char*)Wt + (size_t)(n0 + TF) * (TF * 2);

  f32x4 accn[4][4] = {};
  f32x4 accg[4][4] = {};

  for (int kt = 0; kt < TF / BK; ++kt) {
    if (kt) __syncthreads();
    const int kb0 = kt * (BK * 2);
#pragma unroll
    for (int i = 0; i < 4; ++i) {
      const int o = i * 4096 + tid * 16;
      const int row = o >> 7, kb = o & 127;
      const size_t gsrc = (size_t)row * (TF * 2) + kb0 + kb;
      gl_lds16(Ab + gsrc,  (char*)smA  + i * 4096 + wave * 1024);
      gl_lds16(Bnb + gsrc, (char*)smBn + i * 4096 + wave * 1024);
      gl_lds16(Bgb + gsrc, (char*)smBg + i * 4096 + wave * 1024);
    }
    __syncthreads();
#pragma unroll
    for (int ks = 0; ks < 2; ++ks) {
      f16x8 af[4], bn_[4], bg_[4];
#pragma unroll
      for (int m = 0; m < 4; ++m) {
        const int row = wr * 64 + m * 16 + l15;
        af[m] = *(const f16x8*)((const char*)smA + row * 128 + ks * 64 + l16 * 16);
      }
#pragma unroll
      for (int n = 0; n < 4; ++n) {
        const int row = wc * 64 + n * 16 + l15;
        bn_[n] = *(const f16x8*)((const char*)smBn + row * 128 + ks * 64 + l16 * 16);
        bg_[n] = *(const f16x8*)((const char*)smBg + row * 128 + ks * 64 + l16 * 16);
      }
#pragma unroll
      for (int m = 0; m < 4; ++m)
#pragma unroll
        for (int n = 0; n < 4; ++n) {
          accn[m][n] = __builtin_amdgcn_mfma_f32_16x16x32_f16(af[m], bn_[n], accn[m][n], 0, 0, 0);
          accg[m][n] = __builtin_amdgcn_mfma_f32_16x16x32_f16(af[m], bg_[n], accg[m][n], 0, 0, 0);
        }
    }
  }

#pragma unroll
  for (int n = 0; n < 4; ++n) {
    const int gn = n0 + wc * 64 + n * 16 + l15;
    const float bnl = bv[gn];
    const float bgt = bv[TF + gn];
#pragma unroll
    for (int m = 0; m < 4; ++m) {
#pragma unroll
      for (int j = 0; j < 4; ++j) {
        const int gm = m0 + wr * 64 + m * 16 + l16 * 4 + j;
        const float nl = accn[m][n][j] + bnl;
        const float gt = accg[m][n][j] + bgt;
        const float g = 1.f / (1.f + __expf(-gt));
        const float told = (float)tin[(size_t)gm * TF + gn];
        const float o = g * told + (1.f - g) * fmaxf(nl, 0.f);
        tout[(size_t)gm * TF + gn] = (half_t)o;
      }
    }
  }
}

// ---------------------------------------------------------------- proj ----
__global__ __launch_bounds__(256, 2) void proj_kernel(
    const half_t* __restrict__ tin, const half_t* __restrict__ Wt,
    const float* __restrict__ bv, float* __restrict__ out) {
  __shared__ half_t smA[128 * BK];
  __shared__ half_t smB[128 * BK];
  const int tid = threadIdx.x;
  const int wave = tid >> 6, lane = tid & 63;
  const int l15 = lane & 15, l16 = lane >> 4;
  const int wr = wave >> 1, wc = wave & 1;
  const int m0 = blockIdx.y * 128, n0 = blockIdx.x * 128;

  const char* Ab = (const char*)tin + (size_t)m0 * (TF * 2);
  const char* Bb = (const char*)Wt + (size_t)n0 * (TF * 2);

  f32x4 acc[4][4] = {};

  for (int kt = 0; kt < TF / BK; ++kt) {
    if (kt) __syncthreads();
    const int kb0 = kt * (BK * 2);
#pragma unroll
    for (int i = 0; i < 4; ++i) {
      const int o = i * 4096 + tid * 16;
      const int row = o >> 7, kb = o & 127;
      const size_t gsrc = (size_t)row * (TF * 2) + kb0 + kb;
      gl_lds16(Ab + gsrc, (char*)smA + i * 4096 + wave * 1024);
      gl_lds16(Bb + gsrc, (char*)smB + i * 4096 + wave * 1024);
    }
    __syncthreads();
#pragma unroll
    for (int ks = 0; ks < 2; ++ks) {
      f16x8 af[4], bf[4];
#pragma unroll
      for (int m = 0; m < 4; ++m) {
        const int row = wr * 64 + m * 16 + l15;
        af[m] = *(const f16x8*)((const char*)smA + row * 128 + ks * 64 + l16 * 16);
      }
#pragma unroll
      for (int n = 0; n < 4; ++n) {
        const int row = wc * 64 + n * 16 + l15;
        bf[n] = *(const f16x8*)((const char*)smB + row * 128 + ks * 64 + l16 * 16);
      }
#pragma unroll
      for (int m = 0; m < 4; ++m)
#pragma unroll
        for (int n = 0; n < 4; ++n)
          acc[m][n] = __builtin_amdgcn_mfma_f32_16x16x32_f16(af[m], bf[n], acc[m][n], 0, 0, 0);
    }
  }

#pragma unroll
  for (int n = 0; n < 4; ++n) {
    const int gn = n0 + wc * 64 + n * 16 + l15;
    const float bb = bv[gn];
#pragma unroll
    for (int m = 0; m < 4; ++m) {
#pragma unroll
      for (int j = 0; j < 4; ++j) {
        const int gm = m0 + wr * 64 + m * 16 + l16 * 4 + j;
        out[(size_t)gm * HID + gn] = acc[m][n][j] + bb;
      }
    }
  }
}

// -------------------------------------------------------------- launch ----
extern "C" void kernel_launch(void* const* d_in, const int* in_sizes, int n_in,
                              void* d_out, int out_size, void* d_ws, size_t ws_size,
                              hipStream_t stream) {
  const int*   ids  = (const int*)d_in[0];
  const float* cemb = (const float*)d_in[1];
  const float* cw[7]; const float* cb[7];
  for (int i = 0; i < 7; ++i) {
    cw[i] = (const float*)d_in[2 + 2 * i];
    cb[i] = (const float*)d_in[3 + 2 * i];
  }
  const float* hw_w0  = (const float*)d_in[16];
  const float* hw_b0  = (const float*)d_in[17];
  const float* hw_w1  = (const float*)d_in[18];
  const float* hw_b1  = (const float*)d_in[19];
  const float* proj_w = (const float*)d_in[20];
  const float* proj_b = (const float*)d_in[21];
  float* out = (float*)d_out;

  char* ws = (char*)d_ws;
  half_t* t0h      = (half_t*)(ws);
  half_t* t1h      = (half_t*)(ws + 16777216);
  half_t* wbuf     = (half_t*)(ws + 33554432);   // reused: w0t -> w1t -> pwt
  float*  bias_all = (float*)(ws + 50331648);
  half_t* Wp       = (half_t*)(ws + 50339840);

  wpack_kernel<<<864, 256, 0, stream>>>(
      cw[0], cw[1], cw[2], cw[3], cw[4], cw[5], cw[6],
      cb[0], cb[1], cb[2], cb[3], cb[4], cb[5], cb[6], Wp, bias_all);

  conv_kernel<<<dim3(NTOK / 4, 8), 256, 0, stream>>>(ids, cemb, Wp, bias_all, t0h);

  tcvt_kernel<<<dim3(4096 / 64, TF / 64), 256, 0, stream>>>(hw_w0, wbuf, TF, 4096);
  highway_kernel<<<dim3(TF / 128, NTOK / 128), 256, 0, stream>>>(t0h, wbuf, hw_b0, t1h);

  tcvt_kernel<<<dim3(4096 / 64, TF / 64), 256, 0, stream>>>(hw_w1, wbuf, TF, 4096);
  highway_kernel<<<dim3(TF / 128, NTOK / 128), 256, 0, stream>>>(t1h, wbuf, hw_b1, t0h);

  tcvt_kernel<<<dim3(HID / 64, TF / 64), 256, 0, stream>>>(proj_w, wbuf, TF, HID);
  proj_kernel<<<dim3(HID / 128, NTOK / 128), 256, 0, stream>>>(t0h, wbuf, proj_b, out);
}